// Round 7
// baseline (496.091 us; speedup 1.0000x reference)
//
#include <hip/hip_runtime.h>
#include <hip/hip_bf16.h>

// Problem constants
constexpr int B      = 4;
constexpr int LQ     = 640;
constexpr int LIM    = 1296;
constexpr int LK     = LQ + LIM;   // 1936
constexpr int DM     = 768;
constexpr int NHEAD  = 12;
constexpr int DK     = 64;
constexpr int DFF    = 3072;
constexpr int MAXD   = 100;
constexpr int M_DOC  = B * LQ;     // 2560
constexpr int M_FULL = B * LK;     // 7744
constexpr size_t ML_CNT = (size_t)B * NHEAD * LQ;   // 30720 rows of (m,l) per split

typedef __attribute__((ext_vector_type(8))) short bf16x8_t;   // 8 bf16 = 4 VGPRs
typedef __attribute__((ext_vector_type(4))) float f32x4_t;    // MFMA C/D

__device__ __forceinline__ float b2f(__hip_bfloat16 x) { return __bfloat162float(x); }

__device__ __forceinline__ float ldf(const void* p, size_t i, int f32flag) {
    return f32flag ? ((const float*)p)[i]
                   : b2f(((const __hip_bfloat16*)p)[i]);
}

// async global->LDS, 16 bytes per lane. LDS dest = wave-uniform base + lane*16.
__device__ __forceinline__ void gl_lds16(const void* g, void* l) {
    __builtin_amdgcn_global_load_lds(
        (const __attribute__((address_space(1))) unsigned int*)g,
        (__attribute__((address_space(3))) unsigned int*)l, 16, 0, 0);
}

// ---------------------------------------------------------------------------
__global__ void detect_kernel(const void* __restrict__ g1, int* __restrict__ flagp)
{
    if (blockIdx.x == 0 && threadIdx.x == 0) {
        unsigned u = *(const unsigned*)g1;
        *flagp = ((u & 0xFFFFu) == 0u) ? 1 : 0;
    }
}

// ---------------------------------------------------------------------------
// Transpose 32x32 tile helper body (K x N flagged -> N x K bf16).
// ---------------------------------------------------------------------------
__device__ __forceinline__ void wtrans_tile(const void* W, __hip_bfloat16* Wt,
                                            int f32, int K, int N, int n0, int k0,
                                            __hip_bfloat16 (*t)[33])
{
    const int tx = threadIdx.x & 31, ty = threadIdx.x >> 5;
#pragma unroll
    for (int j = 0; j < 4; ++j) {
        int k = ty + j * 8;
        t[k][tx] = __float2bfloat16(ldf(W, (size_t)(k0 + k) * N + n0 + tx, f32));
    }
    __syncthreads();
#pragma unroll
    for (int j = 0; j < 4; ++j) {
        int n = ty + j * 8;
        Wt[(size_t)(n0 + n) * K + k0 + tx] = t[tx][n];
    }
}

// One launch: Wq,Wk,Wv -> Wt3 rows [0|768|1536..2304), Wo -> WtO. 4*576 blocks.
__global__ __launch_bounds__(256)
void wtransA_kernel(const void* __restrict__ Wq, const void* __restrict__ Wk,
                    const void* __restrict__ Wv, const void* __restrict__ Wo,
                    __hip_bfloat16* __restrict__ Wt3, __hip_bfloat16* __restrict__ WtO,
                    const int* __restrict__ flagp)
{
    __shared__ __hip_bfloat16 t[32][33];
    const int f32 = *flagp;
    const int bx  = blockIdx.x;
    const int wid = bx / 576;
    const int tt  = bx % 576;
    const void* W = (wid == 0) ? Wq : (wid == 1) ? Wk : (wid == 2) ? Wv : Wo;
    __hip_bfloat16* dst = (wid == 3) ? WtO : Wt3 + (size_t)wid * DM * DM;
    wtrans_tile(W, dst, f32, DM, DM, (tt % 24) * 32, (tt / 24) * 32, t);
}

// One launch: W1 (768x3072) -> W1t, W2 (3072x768) -> W2t. 2*2304 blocks.
__global__ __launch_bounds__(256)
void wtransW_kernel(const void* __restrict__ W1, const void* __restrict__ W2,
                    __hip_bfloat16* __restrict__ W1t, __hip_bfloat16* __restrict__ W2t,
                    const int* __restrict__ flagp)
{
    __shared__ __hip_bfloat16 t[32][33];
    const int f32 = *flagp;
    int bx = blockIdx.x;
    const bool second = bx >= 2304;
    const void* W = second ? W2 : W1;
    __hip_bfloat16* dst = second ? W2t : W1t;
    const int K = second ? DFF : DM;
    const int N = second ? DM : DFF;
    const int tt = second ? bx - 2304 : bx;
    const int nt = N / 32;
    wtrans_tile(W, dst, f32, K, N, (tt % nt) * 32, (tt / nt) * 32, t);
}

// ---------------------------------------------------------------------------
// Fused QKV GEMM (unchanged from round 6).
// ---------------------------------------------------------------------------
__global__ __launch_bounds__(256)
void qkv_gemm(const void* __restrict__ Aim,
              const void* __restrict__ Adoc,
              const __hip_bfloat16* __restrict__ Wt3,
              const void* __restrict__ bq,
              const void* __restrict__ bk,
              const void* __restrict__ bv,
              __hip_bfloat16* __restrict__ qb,
              __hip_bfloat16* __restrict__ kb,
              __hip_bfloat16* __restrict__ vb,
              const int* __restrict__ flagp)
{
    __shared__ __hip_bfloat16 Als[128 * 32];
    __shared__ __hip_bfloat16 Bls[128 * 32];

    const int f32  = *flagp;
    const int tid  = threadIdx.x;
    const int lane = tid & 63;
    const int wave = tid >> 6;
    const int quad = lane >> 4;
    const int c16  = lane & 15;
    const int n0   = blockIdx.x * 128;
    const int m0   = blockIdx.y * 128;
    const int wm   = (wave >> 1) * 64;
    const int wn   = (wave & 1) * 64;
    constexpr int K = DM;

    f32x4_t acc[4][4] = {};

    for (int k0 = 0; k0 < K; k0 += 32) {
#pragma unroll
        for (int p = 0; p < 2; ++p) {
            const int lin = p * 64 + lane;
            int row = wave * 32 + (lin >> 2);
            int gr  = m0 + row; if (gr > M_FULL - 1) gr = M_FULL - 1;
            const int kcol = k0 + (lin & 3) * 8;
            int bb = gr / LK;
            int l  = gr - bb * LK;
            const void* base; size_t roff;
            if (l < LIM) { base = Aim;  roff = (size_t)(bb * LIM + l) * K; }
            else         { base = Adoc; roff = (size_t)(bb * LQ + (l - LIM)) * K; }
            union { bf16x8_t v; __hip_bfloat16 h[8]; } pk;
            if (f32) {
                const float4* fp = (const float4*)((const float*)base + roff + kcol);
                float4 a = fp[0], b4 = fp[1];
                pk.h[0] = __float2bfloat16(a.x);  pk.h[1] = __float2bfloat16(a.y);
                pk.h[2] = __float2bfloat16(a.z);  pk.h[3] = __float2bfloat16(a.w);
                pk.h[4] = __float2bfloat16(b4.x); pk.h[5] = __float2bfloat16(b4.y);
                pk.h[6] = __float2bfloat16(b4.z); pk.h[7] = __float2bfloat16(b4.w);
            } else {
                pk.v = *(const bf16x8_t*)((const __hip_bfloat16*)base + roff + kcol);
            }
            *(bf16x8_t*)(Als + wave * 1024 + (size_t)lin * 8) = pk.v;
        }
#pragma unroll
        for (int p = 0; p < 2; ++p) {
            const int lin = p * 64 + lane;
            const int row = wave * 32 + (lin >> 2);
            gl_lds16(Wt3 + (size_t)(n0 + row) * K + k0 + (lin & 3) * 8,
                     Bls + wave * 1024 + p * 512);
        }
        __syncthreads();

        bf16x8_t af[4], bfr[4];
#pragma unroll
        for (int i = 0; i < 4; ++i)
            af[i] = *(const bf16x8_t*)(Als + (wm + i * 16 + c16) * 32 + quad * 8);
#pragma unroll
        for (int j = 0; j < 4; ++j)
            bfr[j] = *(const bf16x8_t*)(Bls + (wn + j * 16 + c16) * 32 + quad * 8);
#pragma unroll
        for (int i = 0; i < 4; ++i)
#pragma unroll
            for (int j = 0; j < 4; ++j)
                acc[i][j] = __builtin_amdgcn_mfma_f32_16x16x32_bf16(af[i], bfr[j], acc[i][j], 0, 0, 0);
        __syncthreads();
    }

    const int seg = n0 / DM;                 // 0=q 1=k 2=v
    const void* bptr = (seg == 0) ? bq : (seg == 1) ? bk : bv;
    const float scl  = (seg == 0) ? 0.125f : 1.f;
#pragma unroll
    for (int j = 0; j < 4; ++j) {
        const int col  = n0 + wn + j * 16 + c16;
        const int ncol = col - seg * DM;
        const float bj = ldf(bptr, ncol, f32);
#pragma unroll
        for (int i = 0; i < 4; ++i) {
            const int rowb = m0 + wm + i * 16 + quad * 4;
#pragma unroll
            for (int r = 0; r < 4; ++r) {
                const int row = rowb + r;
                if (row < M_FULL) {
                    float v = (acc[i][j][r] + bj) * scl;
                    __hip_bfloat16 hv = __float2bfloat16(v);
                    if (seg == 1)      kb[(size_t)row * DM + ncol] = hv;
                    else if (seg == 2) vb[(size_t)row * DM + ncol] = hv;
                    else {
                        int bb = row / LK, l = row - bb * LK;
                        if (l >= LIM)
                            qb[(size_t)(bb * LQ + (l - LIM)) * DM + ncol] = hv;
                    }
                }
            }
        }
    }
}

// Standard MFMA GEMM (bias + relu) for FFN1.
__global__ __launch_bounds__(256)
void mfma_gemm_relu(const __hip_bfloat16* __restrict__ Abf,
                    const __hip_bfloat16* __restrict__ Wt,
                    const void* __restrict__ bias,
                    __hip_bfloat16* __restrict__ Cc,
                    const int* __restrict__ flagp,
                    int M, int N, int K)
{
    __shared__ __hip_bfloat16 Als[128 * 32];
    __shared__ __hip_bfloat16 Bls[128 * 32];

    const int f32  = *flagp;
    const int tid  = threadIdx.x;
    const int lane = tid & 63;
    const int wave = tid >> 6;
    const int quad = lane >> 4;
    const int c16  = lane & 15;
    const int n0   = blockIdx.x * 128;
    const int m0   = blockIdx.y * 128;
    const int wm   = (wave >> 1) * 64;
    const int wn   = (wave & 1) * 64;

    f32x4_t acc[4][4] = {};

    for (int k0 = 0; k0 < K; k0 += 32) {
#pragma unroll
        for (int p = 0; p < 2; ++p) {
            const int lin = p * 64 + lane;
            int row = wave * 32 + (lin >> 2);
            int gr  = m0 + row; if (gr > M - 1) gr = M - 1;
            gl_lds16(Abf + (size_t)gr * K + k0 + (lin & 3) * 8, Als + wave * 1024 + p * 512);
        }
#pragma unroll
        for (int p = 0; p < 2; ++p) {
            const int lin = p * 64 + lane;
            const int row = wave * 32 + (lin >> 2);
            gl_lds16(Wt + (size_t)(n0 + row) * K + k0 + (lin & 3) * 8,
                     Bls + wave * 1024 + p * 512);
        }
        __syncthreads();

        bf16x8_t af[4], bfr[4];
#pragma unroll
        for (int i = 0; i < 4; ++i)
            af[i] = *(const bf16x8_t*)(Als + (wm + i * 16 + c16) * 32 + quad * 8);
#pragma unroll
        for (int j = 0; j < 4; ++j)
            bfr[j] = *(const bf16x8_t*)(Bls + (wn + j * 16 + c16) * 32 + quad * 8);
#pragma unroll
        for (int i = 0; i < 4; ++i)
#pragma unroll
            for (int j = 0; j < 4; ++j)
                acc[i][j] = __builtin_amdgcn_mfma_f32_16x16x32_bf16(af[i], bfr[j], acc[i][j], 0, 0, 0);
        __syncthreads();
    }

#pragma unroll
    for (int j = 0; j < 4; ++j) {
        const int col = n0 + wn + j * 16 + c16;
        const float bj = ldf(bias, col, f32);
#pragma unroll
        for (int i = 0; i < 4; ++i) {
            const int rowb = m0 + wm + i * 16 + quad * 4;
#pragma unroll
            for (int r = 0; r < 4; ++r) {
                const int row = rowb + r;
                if (row < M) {
                    float v = fmaxf(acc[i][j][r] + bj, 0.f);
                    Cc[(size_t)row * N + col] = __float2bfloat16(v);
                }
            }
        }
    }
}

// Split-K MFMA GEMM: f32 atomic accumulate (dest pre-zeroed), grid z = chunk.
__global__ __launch_bounds__(256)
void sk_gemm(const __hip_bfloat16* __restrict__ Abf,
             const __hip_bfloat16* __restrict__ Wt,
             float* __restrict__ Cc,
             int M, int N, int K, int S)
{
    __shared__ __hip_bfloat16 Als[128 * 32];
    __shared__ __hip_bfloat16 Bls[128 * 32];

    const int tid  = threadIdx.x;
    const int lane = tid & 63;
    const int wave = tid >> 6;
    const int quad = lane >> 4;
    const int c16  = lane & 15;
    const int n0   = blockIdx.x * 128;
    const int m0   = blockIdx.y * 128;
    const int wm   = (wave >> 1) * 64;
    const int wn   = (wave & 1) * 64;
    const int kchunk = K / S;
    const int kbeg = blockIdx.z * kchunk;

    f32x4_t acc[4][4] = {};

    for (int k0 = kbeg; k0 < kbeg + kchunk; k0 += 32) {
#pragma unroll
        for (int p = 0; p < 2; ++p) {
            const int lin = p * 64 + lane;
            int row = wave * 32 + (lin >> 2);
            int gr  = m0 + row; if (gr > M - 1) gr = M - 1;
            gl_lds16(Abf + (size_t)gr * K + k0 + (lin & 3) * 8, Als + wave * 1024 + p * 512);
        }
#pragma unroll
        for (int p = 0; p < 2; ++p) {
            const int lin = p * 64 + lane;
            const int row = wave * 32 + (lin >> 2);
            gl_lds16(Wt + (size_t)(n0 + row) * K + k0 + (lin & 3) * 8,
                     Bls + wave * 1024 + p * 512);
        }
        __syncthreads();

        bf16x8_t af[4], bfr[4];
#pragma unroll
        for (int i = 0; i < 4; ++i)
            af[i] = *(const bf16x8_t*)(Als + (wm + i * 16 + c16) * 32 + quad * 8);
#pragma unroll
        for (int j = 0; j < 4; ++j)
            bfr[j] = *(const bf16x8_t*)(Bls + (wn + j * 16 + c16) * 32 + quad * 8);
#pragma unroll
        for (int i = 0; i < 4; ++i)
#pragma unroll
            for (int j = 0; j < 4; ++j)
                acc[i][j] = __builtin_amdgcn_mfma_f32_16x16x32_bf16(af[i], bfr[j], acc[i][j], 0, 0, 0);
        __syncthreads();
    }

#pragma unroll
    for (int j = 0; j < 4; ++j) {
        const int col = n0 + wn + j * 16 + c16;
#pragma unroll
        for (int i = 0; i < 4; ++i) {
            const int rowb = m0 + wm + i * 16 + quad * 4;
#pragma unroll
            for (int r = 0; r < 4; ++r) {
                const int row = rowb + r;
                if (row < M) atomicAdd(&Cc[(size_t)row * N + col], acc[i][j][r]);
            }
        }
    }
}

// ---------------------------------------------------------------------------
// MFMA flash attention, K-split S=2 (flash-decoding). Grid (10, 12, B*2):
// b = z&3, s = z>>2. Split s covers K rows [s*1024, min(LK,(s+1)*1024...)).
// Writes UNNORMALIZED partial O (bf16, ctx layout) + per-(b,h,q) m,l (f32).
// ---------------------------------------------------------------------------
__global__ __launch_bounds__(256)
void attn_part_kernel(const __hip_bfloat16* __restrict__ Qb,
                      const __hip_bfloat16* __restrict__ Kb,
                      const __hip_bfloat16* __restrict__ Vb,
                      const int* __restrict__ dqx, const int* __restrict__ dqy,
                      const int* __restrict__ imx, const int* __restrict__ imy,
                      const void* __restrict__ bias_x,
                      const void* __restrict__ bias_y,
                      __hip_bfloat16* __restrict__ p0,
                      __hip_bfloat16* __restrict__ p1,
                      float* __restrict__ mlbase,   // [s][m|l][B*NHEAD*LQ]
                      const int* __restrict__ flagp)
{
    constexpr int QT = 64, KT = 64;
    constexpr int QROW = 72;
    constexpr int VROW = 88;
    __shared__ __hip_bfloat16 Qs[QT * QROW];
    __shared__ __hip_bfloat16 Ks[KT * QROW];
    __shared__ __hip_bfloat16 Vt[DK * VROW];
    __shared__ __hip_bfloat16 Ps[QT * QROW];
    __shared__ float bxs[2 * MAXD + 1], bys[2 * MAXD + 1];
    __shared__ int   qxs[QT], qys[QT], kxt[KT], kyt[KT];

    const int f32  = *flagp;
    const int tid  = threadIdx.x;
    const int lane = tid & 63;
    const int wave = tid >> 6;
    const int quad = lane >> 4;
    const int c16  = lane & 15;
    const int h    = blockIdx.y;
    const int b    = blockIdx.z & 3;
    const int s    = blockIdx.z >> 2;
    const int q0   = blockIdx.x * QT;
    const int kbeg = s * 1024;
    const int kend = s ? LK : 1024;

    __hip_bfloat16* Op = s ? p1 : p0;
    float* mp = mlbase + (size_t)s * 2 * ML_CNT;
    float* lp = mp + ML_CNT;

    {
        const int qr = lane, c = wave;
        const __hip_bfloat16* src = Qb + ((size_t)(b * LQ + q0 + qr)) * DM + h * DK + c * 16;
        *(bf16x8_t*)(Qs + qr * QROW + c * 16)     = *(const bf16x8_t*)src;
        *(bf16x8_t*)(Qs + qr * QROW + c * 16 + 8) = *(const bf16x8_t*)(src + 8);
    }
    if (tid < QT) { qxs[tid] = dqx[b * LQ + q0 + tid]; qys[tid] = dqy[b * LQ + q0 + tid]; }
    for (int i = tid; i < 2 * MAXD + 1; i += 256) {
        bxs[i] = ldf(bias_x, (size_t)i * NHEAD + h, f32);
        bys[i] = ldf(bias_y, (size_t)i * NHEAD + h, f32);
    }

    f32x4_t O[4] = {};
    float m_r[4], l_r[4];
#pragma unroll
    for (int r = 0; r < 4; ++r) { m_r[r] = -1e30f; l_r[r] = 0.f; }

    for (int k0 = kbeg; k0 < kend; k0 += KT) {
        __syncthreads();
        {
            const int kk = lane, c = wave;
            const int kg = k0 + kk;
            const int kgc = kg < LK ? kg : LK - 1;
            const __hip_bfloat16* ksrc = Kb + ((size_t)(b * LK + kgc)) * DM + h * DK + c * 16;
            *(bf16x8_t*)(Ks + kk * QROW + c * 16)     = *(const bf16x8_t*)ksrc;
            *(bf16x8_t*)(Ks + kk * QROW + c * 16 + 8) = *(const bf16x8_t*)(ksrc + 8);
            const __hip_bfloat16* vsrc = Vb + ((size_t)(b * LK + kgc)) * DM + h * DK + c * 16;
            union { bf16x8_t v; __hip_bfloat16 hh[8]; } u0, u1;
            u0.v = *(const bf16x8_t*)vsrc;
            u1.v = *(const bf16x8_t*)(vsrc + 8);
#pragma unroll
            for (int t = 0; t < 8; ++t) {
                Vt[(c * 16 + t) * VROW + kk]     = u0.hh[t];
                Vt[(c * 16 + 8 + t) * VROW + kk] = u1.hh[t];
            }
        }
        if (tid < KT) {
            int kg = k0 + tid, xx = 0, yy = 0;
            if (kg < LK) {
                if (kg < LIM) { xx = imx[b * LIM + kg];     yy = imy[b * LIM + kg]; }
                else          { xx = dqx[b * LQ + kg - LIM]; yy = dqy[b * LQ + kg - LIM]; }
            }
            kxt[tid] = xx; kyt[tid] = yy;
        }
        __syncthreads();

        bf16x8_t aq0 = *(const bf16x8_t*)(Qs + (wave * 16 + c16) * QROW + quad * 8);
        bf16x8_t aq1 = *(const bf16x8_t*)(Qs + (wave * 16 + c16) * QROW + 32 + quad * 8);
        f32x4_t S[4];
#pragma unroll
        for (int jn = 0; jn < 4; ++jn) {
            bf16x8_t bk0 = *(const bf16x8_t*)(Ks + (jn * 16 + c16) * QROW + quad * 8);
            bf16x8_t bk1 = *(const bf16x8_t*)(Ks + (jn * 16 + c16) * QROW + 32 + quad * 8);
            f32x4_t acc = {0.f, 0.f, 0.f, 0.f};
            acc = __builtin_amdgcn_mfma_f32_16x16x32_bf16(aq0, bk0, acc, 0, 0, 0);
            acc = __builtin_amdgcn_mfma_f32_16x16x32_bf16(aq1, bk1, acc, 0, 0, 0);
            S[jn] = acc;
        }
#pragma unroll
        for (int jn = 0; jn < 4; ++jn) {
            const int kcol = jn * 16 + c16;
            const bool ok  = (k0 + kcol) < LK;
            const int kx = kxt[kcol], ky = kyt[kcol];
#pragma unroll
            for (int r = 0; r < 4; ++r) {
                const int qrow = wave * 16 + quad * 4 + r;
                int rx = min(max(qxs[qrow] - kx, -MAXD), MAXD) + MAXD;
                int ry = min(max(qys[qrow] - ky, -MAXD), MAXD) + MAXD;
                float v = S[jn][r] + bxs[rx] + bys[ry];
                S[jn][r] = ok ? v : -1e30f;
            }
        }
        float alpha[4];
#pragma unroll
        for (int r = 0; r < 4; ++r) {
            float mx = fmaxf(fmaxf(S[0][r], S[1][r]), fmaxf(S[2][r], S[3][r]));
            mx = fmaxf(mx, __shfl_xor(mx, 1));
            mx = fmaxf(mx, __shfl_xor(mx, 2));
            mx = fmaxf(mx, __shfl_xor(mx, 4));
            mx = fmaxf(mx, __shfl_xor(mx, 8));
            const float mt = fmaxf(m_r[r], mx);
            const float al = __expf(m_r[r] - mt);
            float sum = 0.f;
#pragma unroll
            for (int jn = 0; jn < 4; ++jn) {
                float p = __expf(S[jn][r] - mt);
                S[jn][r] = p;
                sum += p;
            }
            sum += __shfl_xor(sum, 1);
            sum += __shfl_xor(sum, 2);
            sum += __shfl_xor(sum, 4);
            sum += __shfl_xor(sum, 8);
            m_r[r] = mt;
            l_r[r] = l_r[r] * al + sum;
            alpha[r] = al;
        }
#pragma unroll
        for (int jn = 0; jn < 4; ++jn)
#pragma unroll
            for (int r = 0; r < 4; ++r)
                Ps[(wave * 16 + quad * 4 + r) * QROW + jn * 16 + c16] = __float2bfloat16(S[jn][r]);
#pragma unroll
        for (int jd = 0; jd < 4; ++jd)
#pragma unroll
            for (int r = 0; r < 4; ++r) O[jd][r] *= alpha[r];
        bf16x8_t ap0 = *(const bf16x8_t*)(Ps + (wave * 16 + c16) * QROW + quad * 8);
        bf16x8_t ap1 = *(const bf16x8_t*)(Ps + (wave * 16 + c16) * QROW + 32 + quad * 8);
#pragma unroll
        for (int jd = 0; jd < 4; ++jd) {
            bf16x8_t bv0 = *(const bf16x8_t*)(Vt + (jd * 16 + c16) * VROW + quad * 8);
            bf16x8_t bv1 = *(const bf16x8_t*)(Vt + (jd * 16 + c16) * VROW + 32 + quad * 8);
            O[jd] = __builtin_amdgcn_mfma_f32_16x16x32_bf16(ap0, bv0, O[jd], 0, 0, 0);
            O[jd] = __builtin_amdgcn_mfma_f32_16x16x32_bf16(ap1, bv1, O[jd], 0, 0, 0);
        }
    }

    // Epilogue: unnormalized partial O + (m,l)
#pragma unroll
    for (int r = 0; r < 4; ++r) {
        const int ql = wave * 16 + quad * 4 + r;
        const size_t grow = (size_t)(b * LQ + q0 + ql);
#pragma unroll
        for (int jd = 0; jd < 4; ++jd)
            Op[grow * DM + h * DK + jd * 16 + c16] = __float2bfloat16(O[jd][r]);
        if (c16 == 0) {
            size_t mli = ((size_t)b * NHEAD + h) * LQ + q0 + ql;
            mp[mli] = m_r[r];
            lp[mli] = l_r[r];
        }
    }
}

// Merge the two K-splits into ctx (in-place over p0) and zero aof.
__global__ __launch_bounds__(256)
void attn_merge_kernel(const __hip_bfloat16* __restrict__ p0,
                       const __hip_bfloat16* __restrict__ p1,
                       const float* __restrict__ mlbase,
                       __hip_bfloat16* __restrict__ ctx,
                       float* __restrict__ aof)
{
    const int row = blockIdx.x;            // (b,q) flat
    const int b = row / LQ, q = row - b * LQ;
    const int tid = threadIdx.x;
#pragma unroll
    for (int i = 0; i < 3; ++i) {
        const int c = tid + i * 256;
        const int h = c >> 6;
        const size_t mli = ((size_t)b * NHEAD + h) * LQ + q;
        const float m0 = mlbase[mli],              l0 = mlbase[ML_CNT + mli];
        const float m1 = mlbase[2 * ML_CNT + mli], l1 = mlbase[3 * ML_CNT + mli];
        const float mm = fmaxf(m0, m1);
        const float w0 = __expf(m0 - mm), w1 = __expf(m1 - mm);
        const float denom = l0 * w0 + l1 * w1;
        const size_t idx = (size_t)row * DM + c;
        const float v = (b2f(p0[idx]) * w0 + b2f(p1[idx]) * w1) / denom;
        ctx[idx] = __float2bfloat16(v);    // in-place over p0 (same idx) - safe
        aof[idx] = 0.f;
    }
}

// ---------------------------------------------------------------------------
// LayerNorm over 768 with folded bias: x = A + F32acc + bias2.
//  MODE 0: A = flagged Xin -> bf16 ws out; also zeroes zbuf (next accumulator).
//  MODE 1: A = bf16 Xb     -> flagged-dtype d_out.
// ---------------------------------------------------------------------------
template<int MODE>
__global__ __launch_bounds__(256)
void ln_kernel(const void* __restrict__ Xin,
               const __hip_bfloat16* __restrict__ Xb,
               const float* __restrict__ Xf2f,
               const void* __restrict__ bias2,
               const void* __restrict__ g,
               const void* __restrict__ be,
               __hip_bfloat16* __restrict__ outb,
               void* __restrict__ outv,
               float* __restrict__ zbuf,
               const int* __restrict__ flagp)
{
    __shared__ float red1[256], red2[256];
    const int f32 = *flagp;
    const int row = blockIdx.x;
    const int tid = threadIdx.x;

    float x[3];
#pragma unroll
    for (int i = 0; i < 3; ++i) {
        int c = tid + i * 256;
        size_t idx = (size_t)row * DM + c;
        float a  = (MODE == 0) ? ldf(Xin, idx, f32) : b2f(Xb[idx]);
        x[i] = a + Xf2f[idx] + ldf(bias2, c, f32);
    }
    float s1 = x[0] + x[1] + x[2];
    float s2 = x[0] * x[0] + x[1] * x[1] + x[2] * x[2];
    red1[tid] = s1;
    red2[tid] = s2;
    __syncthreads();
    for (int off = 128; off > 0; off >>= 1) {
        if (tid < off) {
            red1[tid] += red1[tid + off];
            red2[tid] += red2[tid + off];
        }
        __syncthreads();
    }
    float mu   = red1[0] * (1.f / DM);
    float var  = red2[0] * (1.f / DM) - mu * mu;
    float rstd = rsqrtf(var + 1e-5f);
#pragma unroll
    for (int i = 0; i < 3; ++i) {
        int c = tid + i * 256;
        size_t idx = (size_t)row * DM + c;
        float v = (x[i] - mu) * rstd * ldf(g, c, f32) + ldf(be, c, f32);
        if (MODE == 0) {
            outb[idx] = __float2bfloat16(v);
            zbuf[idx] = 0.f;
        } else {
            if (f32) ((float*)outv)[idx] = v;
            else     ((__hip_bfloat16*)outv)[idx] = __float2bfloat16(v);
        }
    }
}

// ---------------------------------------------------------------------------
extern "C" void kernel_launch(void* const* d_in, const int* in_sizes, int n_in,
                              void* d_out, int out_size, void* d_ws, size_t ws_size,
                              hipStream_t stream)
{
    const void* docqa = d_in[0];
    const void* im    = d_in[1];
    const int* dqx = (const int*)d_in[2];
    const int* dqy = (const int*)d_in[3];
    const int* imx = (const int*)d_in[4];
    const int* imy = (const int*)d_in[5];
    const void* Wq = d_in[6];
    const void* bq = d_in[7];
    const void* Wk = d_in[8];
    const void* bk = d_in[9];
    const void* Wv = d_in[10];
    const void* bv = d_in[11];
    const void* Wo = d_in[12];
    const void* bo = d_in[13];
    const void* bias_x = d_in[14];
    const void* bias_y = d_in[15];
    const void* W1 = d_in[16];
    const void* b1 = d_in[17];
    const void* W2 = d_in[18];
    const void* b2 = d_in[19];
    const void* g1  = d_in[20];
    const void* be1 = d_in[21];
    const void* g2  = d_in[22];
    const void* be2 = d_in[23];

    // Workspace pool: 39.6 MB total, proven since round 3 (DO NOT GROW —
    // a 60 MB layout corrupted neighbors in round 2).
    //   flag @0; qb 3.93M; kb 11.89M; vb 11.89M; cb 11.89M   [bytes]
    // cb internal carve (byte offsets), lifetimes stream-sequenced:
    //   [0, 3.54M)   Wt3            (dead after qkv)
    //   [0, 3.93M)   p0 -> ctx -> src1
    //   [3.93, 7.86M) p1            (dead after merge)
    //   [7.86, 8.36M) ml (4 x 30720 f32)   (dead after merge)
    //   [8.36, 9.54M) WtO           (dead after skWo)
    //   [3.93, 11.79M) fof f32      (after LN1; over dead p1/ml/WtO)
    // vb: v -> aof f32 -> W1t[0,4.72M)+W2t[4.72,9.44M)
    // qb+kb: q,k -> mid bf16 (15.73M <= 15.82M)
    char* w = (char*)d_ws;
    int*            flagp = (int*)w;
    __hip_bfloat16* qb  = (__hip_bfloat16*)(w + 256);
    __hip_bfloat16* kb  = qb + (size_t)M_DOC  * DM;
    __hip_bfloat16* vb  = kb + (size_t)M_FULL * DM;
    __hip_bfloat16* cb  = vb + (size_t)M_FULL * DM;
    char* cbB = (char*)cb;

    __hip_bfloat16* Wt3  = cb;
    __hip_bfloat16* p0   = cb;
    __hip_bfloat16* p1   = (__hip_bfloat16*)(cbB + 3932160);
    float*          mlb  = (float*)(cbB + 7864320);
    __hip_bfloat16* WtO  = (__hip_bfloat16*)(cbB + 8355840);
    __hip_bfloat16* ctx  = cb;
    __hip_bfloat16* src1 = cb;
    float*          fof  = (float*)(cbB + 3932160);
    float*          aof  = (float*)vb;
    __hip_bfloat16* W1t  = vb;
    __hip_bfloat16* W2t  = vb + (size_t)DFF * DM;
    __hip_bfloat16* mid  = qb;

    dim3 blk(256);

    detect_kernel<<<dim3(1), dim3(64), 0, stream>>>(g1, flagp);
    // All attention-side weight transposes in one launch
    wtransA_kernel<<<dim3(4 * 576), blk, 0, stream>>>(Wq, Wk, Wv, Wo, Wt3, WtO, flagp);
    // Fused q/k/v projection
    qkv_gemm<<<dim3(3 * DM / 128, (M_FULL + 127) / 128), blk, 0, stream>>>(
        im, docqa, Wt3, bq, bk, bv, qb, kb, vb, flagp);
    // Attention, K-split S=2 -> partials + (m,l)
    attn_part_kernel<<<dim3(LQ / 64, NHEAD, B * 2), blk, 0, stream>>>(
        qb, kb, vb, dqx, dqy, imx, imy, bias_x, bias_y, p0, p1, mlb, flagp);
    // Merge partials -> ctx; zero aof (v dead)
    attn_merge_kernel<<<dim3(M_DOC), blk, 0, stream>>>(p0, p1, mlb, ctx, aof);
    // attn_out: split-K S=8 atomics into aof. bo folded into LN1.
    sk_gemm<<<dim3(DM / 128, M_DOC / 128, 8), blk, 0, stream>>>(
        ctx, WtO, aof, M_DOC, DM, DM, 8);
    // src1 = LN(docqa + aof + bo); also zero fof
    ln_kernel<0><<<dim3(M_DOC), blk, 0, stream>>>(
        docqa, nullptr, aof, bo, g1, be1, src1, nullptr, fof, flagp);
    // FFN weight transposes in one launch (overwrite dead aof region)
    wtransW_kernel<<<dim3(2 * 2304), blk, 0, stream>>>(W1, W2, W1t, W2t, flagp);
    // mid = relu(src1 @ W1 + b1)
    mfma_gemm_relu<<<dim3(DFF / 128, M_DOC / 128), blk, 0, stream>>>(
        src1, W1t, b1, mid, flagp, M_DOC, DFF, DM);
    // ffn: split-K S=8 atomics into fof. b2 folded into LN2.
    sk_gemm<<<dim3(DM / 128, M_DOC / 128, 8), blk, 0, stream>>>(
        mid, W2t, fof, M_DOC, DM, DFF, 8);
    // out = LN(src1 + fof + b2)
    ln_kernel<1><<<dim3(M_DOC), blk, 0, stream>>>(
        nullptr, src1, fof, b2, g2, be2, nullptr, d_out, nullptr, flagp);
}

// Round 8
// 451.238 us; speedup vs baseline: 1.0994x; 1.0994x over previous
//
#include <hip/hip_runtime.h>
#include <hip/hip_bf16.h>

// Problem constants
constexpr int B      = 4;
constexpr int LQ     = 640;
constexpr int LIM    = 1296;
constexpr int LK     = LQ + LIM;   // 1936
constexpr int DM     = 768;
constexpr int NHEAD  = 12;
constexpr int DK     = 64;
constexpr int DFF    = 3072;
constexpr int MAXD   = 100;
constexpr int M_DOC  = B * LQ;     // 2560
constexpr int M_FULL = B * LK;     // 7744
constexpr size_t ML_CNT = (size_t)B * NHEAD * LQ;   // 30720 (m,l) rows per split

typedef __attribute__((ext_vector_type(8))) short bf16x8_t;   // 8 bf16 = 4 VGPRs
typedef __attribute__((ext_vector_type(4))) float f32x4_t;    // MFMA C/D

__device__ __forceinline__ float b2f(__hip_bfloat16 x) { return __bfloat162float(x); }

__device__ __forceinline__ float ldf(const void* p, size_t i, int f32flag) {
    return f32flag ? ((const float*)p)[i]
                   : b2f(((const __hip_bfloat16*)p)[i]);
}

// async global->LDS, 16 bytes per lane. LDS dest = wave-uniform base + lane*16.
__device__ __forceinline__ void gl_lds16(const void* g, void* l) {
    __builtin_amdgcn_global_load_lds(
        (const __attribute__((address_space(1))) unsigned int*)g,
        (__attribute__((address_space(3))) unsigned int*)l, 16, 0, 0);
}

// ---------------------------------------------------------------------------
// prep: dtype flag + fused per-batch K-side coordinate arrays cx/cy[b][LK].
// ---------------------------------------------------------------------------
__global__ __launch_bounds__(256)
void prep_kernel(const void* __restrict__ g1, int* __restrict__ flagp,
                 const int* __restrict__ dqx, const int* __restrict__ dqy,
                 const int* __restrict__ imx, const int* __restrict__ imy,
                 int* __restrict__ cx, int* __restrict__ cy)
{
    if (blockIdx.x == 0 && threadIdx.x == 0) {
        unsigned u = *(const unsigned*)g1;
        *flagp = ((u & 0xFFFFu) == 0u) ? 1 : 0;
    }
    int idx = blockIdx.x * 256 + threadIdx.x;
    for (; idx < B * LK; idx += gridDim.x * 256) {
        int b = idx / LK, l = idx - b * LK;
        cx[idx] = (l < LIM) ? imx[b * LIM + l] : dqx[b * LQ + l - LIM];
        cy[idx] = (l < LIM) ? imy[b * LIM + l] : dqy[b * LQ + l - LIM];
    }
}

// ---------------------------------------------------------------------------
// Transpose 32x32 tile helper (K x N flagged -> N x K bf16).
// ---------------------------------------------------------------------------
__device__ __forceinline__ void wtrans_tile(const void* W, __hip_bfloat16* Wt,
                                            int f32, int K, int N, int n0, int k0,
                                            __hip_bfloat16 (*t)[33])
{
    const int tx = threadIdx.x & 31, ty = threadIdx.x >> 5;
#pragma unroll
    for (int j = 0; j < 4; ++j) {
        int k = ty + j * 8;
        t[k][tx] = __float2bfloat16(ldf(W, (size_t)(k0 + k) * N + n0 + tx, f32));
    }
    __syncthreads();
#pragma unroll
    for (int j = 0; j < 4; ++j) {
        int n = ty + j * 8;
        Wt[(size_t)(n0 + n) * K + k0 + tx] = t[tx][n];
    }
}

__global__ __launch_bounds__(256)
void wtransA_kernel(const void* __restrict__ Wq, const void* __restrict__ Wk,
                    const void* __restrict__ Wv, const void* __restrict__ Wo,
                    __hip_bfloat16* __restrict__ Wt3, __hip_bfloat16* __restrict__ WtO,
                    const int* __restrict__ flagp)
{
    __shared__ __hip_bfloat16 t[32][33];
    const int f32 = *flagp;
    const int bx  = blockIdx.x;
    const int wid = bx / 576;
    const int tt  = bx % 576;
    const void* W = (wid == 0) ? Wq : (wid == 1) ? Wk : (wid == 2) ? Wv : Wo;
    __hip_bfloat16* dst = (wid == 3) ? WtO : Wt3 + (size_t)wid * DM * DM;
    wtrans_tile(W, dst, f32, DM, DM, (tt % 24) * 32, (tt / 24) * 32, t);
}

__global__ __launch_bounds__(256)
void wtransW_kernel(const void* __restrict__ W1, const void* __restrict__ W2,
                    __hip_bfloat16* __restrict__ W1t, __hip_bfloat16* __restrict__ W2t,
                    const int* __restrict__ flagp)
{
    __shared__ __hip_bfloat16 t[32][33];
    const int f32 = *flagp;
    int bx = blockIdx.x;
    const bool second = bx >= 2304;
    const void* W = second ? W2 : W1;
    __hip_bfloat16* dst = second ? W2t : W1t;
    const int K = second ? DFF : DM;
    const int N = second ? DM : DFF;
    const int tt = second ? bx - 2304 : bx;
    const int nt = N / 32;
    wtrans_tile(W, dst, f32, K, N, (tt % nt) * 32, (tt / nt) * 32, t);
}

// ---------------------------------------------------------------------------
// Fused QKV GEMM. q (doc rows, *1/8) and k written row-major; V written
// TRANSPOSED per (b,h): vtb[((b*NHEAD+h)*DK + d) * LK + kk].
// ---------------------------------------------------------------------------
__global__ __launch_bounds__(256)
void qkv_gemm(const void* __restrict__ Aim,
              const void* __restrict__ Adoc,
              const __hip_bfloat16* __restrict__ Wt3,
              const void* __restrict__ bq,
              const void* __restrict__ bk,
              const void* __restrict__ bv,
              __hip_bfloat16* __restrict__ qb,
              __hip_bfloat16* __restrict__ kb,
              __hip_bfloat16* __restrict__ vtb,
              const int* __restrict__ flagp)
{
    __shared__ __hip_bfloat16 Als[128 * 32];
    __shared__ __hip_bfloat16 Bls[128 * 32];

    const int f32  = *flagp;
    const int tid  = threadIdx.x;
    const int lane = tid & 63;
    const int wave = tid >> 6;
    const int quad = lane >> 4;
    const int c16  = lane & 15;
    const int n0   = blockIdx.x * 128;
    const int m0   = blockIdx.y * 128;
    const int wm   = (wave >> 1) * 64;
    const int wn   = (wave & 1) * 64;
    constexpr int K = DM;

    f32x4_t acc[4][4] = {};

    for (int k0 = 0; k0 < K; k0 += 32) {
#pragma unroll
        for (int p = 0; p < 2; ++p) {
            const int lin = p * 64 + lane;
            int row = wave * 32 + (lin >> 2);
            int gr  = m0 + row; if (gr > M_FULL - 1) gr = M_FULL - 1;
            const int kcol = k0 + (lin & 3) * 8;
            int bb = gr / LK;
            int l  = gr - bb * LK;
            const void* base; size_t roff;
            if (l < LIM) { base = Aim;  roff = (size_t)(bb * LIM + l) * K; }
            else         { base = Adoc; roff = (size_t)(bb * LQ + (l - LIM)) * K; }
            union { bf16x8_t v; __hip_bfloat16 h[8]; } pk;
            if (f32) {
                const float4* fp = (const float4*)((const float*)base + roff + kcol);
                float4 a = fp[0], b4 = fp[1];
                pk.h[0] = __float2bfloat16(a.x);  pk.h[1] = __float2bfloat16(a.y);
                pk.h[2] = __float2bfloat16(a.z);  pk.h[3] = __float2bfloat16(a.w);
                pk.h[4] = __float2bfloat16(b4.x); pk.h[5] = __float2bfloat16(b4.y);
                pk.h[6] = __float2bfloat16(b4.z); pk.h[7] = __float2bfloat16(b4.w);
            } else {
                pk.v = *(const bf16x8_t*)((const __hip_bfloat16*)base + roff + kcol);
            }
            *(bf16x8_t*)(Als + wave * 1024 + (size_t)lin * 8) = pk.v;
        }
#pragma unroll
        for (int p = 0; p < 2; ++p) {
            const int lin = p * 64 + lane;
            const int row = wave * 32 + (lin >> 2);
            gl_lds16(Wt3 + (size_t)(n0 + row) * K + k0 + (lin & 3) * 8,
                     Bls + wave * 1024 + p * 512);
        }
        __syncthreads();

        bf16x8_t af[4], bfr[4];
#pragma unroll
        for (int i = 0; i < 4; ++i)
            af[i] = *(const bf16x8_t*)(Als + (wm + i * 16 + c16) * 32 + quad * 8);
#pragma unroll
        for (int j = 0; j < 4; ++j)
            bfr[j] = *(const bf16x8_t*)(Bls + (wn + j * 16 + c16) * 32 + quad * 8);
#pragma unroll
        for (int i = 0; i < 4; ++i)
#pragma unroll
            for (int j = 0; j < 4; ++j)
                acc[i][j] = __builtin_amdgcn_mfma_f32_16x16x32_bf16(af[i], bfr[j], acc[i][j], 0, 0, 0);
        __syncthreads();
    }

    const int seg = n0 / DM;                 // 0=q 1=k 2=v
    const void* bptr = (seg == 0) ? bq : (seg == 1) ? bk : bv;
#pragma unroll
    for (int j = 0; j < 4; ++j) {
        const int col  = n0 + wn + j * 16 + c16;
        const int ncol = col - seg * DM;
        const float bj = ldf(bptr, ncol, f32);
        if (seg == 2) {
            // V transposed: vtb[((bb*NHEAD+h)*DK+d)*LK + kk]
            const int h = ncol >> 6, d = ncol & 63;
#pragma unroll
            for (int i = 0; i < 4; ++i) {
                const int rowb = m0 + wm + i * 16 + quad * 4;
                const int bb0  = rowb / LK;
                const int l0   = rowb - bb0 * LK;
                if (l0 + 3 < LK && rowb + 3 < M_FULL) {
                    union { ushort4 u4; __hip_bfloat16 hh[4]; } pk;
#pragma unroll
                    for (int r = 0; r < 4; ++r)
                        pk.hh[r] = __float2bfloat16(acc[i][j][r] + bj);
                    *(ushort4*)(vtb + ((size_t)((bb0 * NHEAD + h) * DK + d)) * LK + l0) = pk.u4;
                } else {
#pragma unroll
                    for (int r = 0; r < 4; ++r) {
                        const int row = rowb + r;
                        if (row < M_FULL) {
                            int bb = row / LK, l = row - bb * LK;
                            vtb[((size_t)((bb * NHEAD + h) * DK + d)) * LK + l] =
                                __float2bfloat16(acc[i][j][r] + bj);
                        }
                    }
                }
            }
        } else {
            const float scl = (seg == 0) ? 0.125f : 1.f;
#pragma unroll
            for (int i = 0; i < 4; ++i) {
                const int rowb = m0 + wm + i * 16 + quad * 4;
#pragma unroll
                for (int r = 0; r < 4; ++r) {
                    const int row = rowb + r;
                    if (row < M_FULL) {
                        __hip_bfloat16 hv = __float2bfloat16((acc[i][j][r] + bj) * scl);
                        if (seg == 1) kb[(size_t)row * DM + ncol] = hv;
                        else {
                            int bb = row / LK, l = row - bb * LK;
                            if (l >= LIM)
                                qb[(size_t)(bb * LQ + (l - LIM)) * DM + ncol] = hv;
                        }
                    }
                }
            }
        }
    }
}

// Standard MFMA GEMM (bias + relu) for FFN1.
__global__ __launch_bounds__(256)
void mfma_gemm_relu(const __hip_bfloat16* __restrict__ Abf,
                    const __hip_bfloat16* __restrict__ Wt,
                    const void* __restrict__ bias,
                    __hip_bfloat16* __restrict__ Cc,
                    const int* __restrict__ flagp,
                    int M, int N, int K)
{
    __shared__ __hip_bfloat16 Als[128 * 32];
    __shared__ __hip_bfloat16 Bls[128 * 32];

    const int f32  = *flagp;
    const int tid  = threadIdx.x;
    const int lane = tid & 63;
    const int wave = tid >> 6;
    const int quad = lane >> 4;
    const int c16  = lane & 15;
    const int n0   = blockIdx.x * 128;
    const int m0   = blockIdx.y * 128;
    const int wm   = (wave >> 1) * 64;
    const int wn   = (wave & 1) * 64;

    f32x4_t acc[4][4] = {};

    for (int k0 = 0; k0 < K; k0 += 32) {
#pragma unroll
        for (int p = 0; p < 2; ++p) {
            const int lin = p * 64 + lane;
            int row = wave * 32 + (lin >> 2);
            int gr  = m0 + row; if (gr > M - 1) gr = M - 1;
            gl_lds16(Abf + (size_t)gr * K + k0 + (lin & 3) * 8, Als + wave * 1024 + p * 512);
        }
#pragma unroll
        for (int p = 0; p < 2; ++p) {
            const int lin = p * 64 + lane;
            const int row = wave * 32 + (lin >> 2);
            gl_lds16(Wt + (size_t)(n0 + row) * K + k0 + (lin & 3) * 8,
                     Bls + wave * 1024 + p * 512);
        }
        __syncthreads();

        bf16x8_t af[4], bfr[4];
#pragma unroll
        for (int i = 0; i < 4; ++i)
            af[i] = *(const bf16x8_t*)(Als + (wm + i * 16 + c16) * 32 + quad * 8);
#pragma unroll
        for (int j = 0; j < 4; ++j)
            bfr[j] = *(const bf16x8_t*)(Bls + (wn + j * 16 + c16) * 32 + quad * 8);
#pragma unroll
        for (int i = 0; i < 4; ++i)
#pragma unroll
            for (int j = 0; j < 4; ++j)
                acc[i][j] = __builtin_amdgcn_mfma_f32_16x16x32_bf16(af[i], bfr[j], acc[i][j], 0, 0, 0);
        __syncthreads();
    }

#pragma unroll
    for (int j = 0; j < 4; ++j) {
        const int col = n0 + wn + j * 16 + c16;
        const float bj = ldf(bias, col, f32);
#pragma unroll
        for (int i = 0; i < 4; ++i) {
            const int rowb = m0 + wm + i * 16 + quad * 4;
#pragma unroll
            for (int r = 0; r < 4; ++r) {
                const int row = rowb + r;
                if (row < M) {
                    float v = fmaxf(acc[i][j][r] + bj, 0.f);
                    Cc[(size_t)row * N + col] = __float2bfloat16(v);
                }
            }
        }
    }
}

// Split-K MFMA GEMM: f32 atomic accumulate (dest pre-zeroed), grid z = chunk.
__global__ __launch_bounds__(256)
void sk_gemm(const __hip_bfloat16* __restrict__ Abf,
             const __hip_bfloat16* __restrict__ Wt,
             float* __restrict__ Cc,
             int M, int N, int K, int S)
{
    __shared__ __hip_bfloat16 Als[128 * 32];
    __shared__ __hip_bfloat16 Bls[128 * 32];

    const int tid  = threadIdx.x;
    const int lane = tid & 63;
    const int wave = tid >> 6;
    const int quad = lane >> 4;
    const int c16  = lane & 15;
    const int n0   = blockIdx.x * 128;
    const int m0   = blockIdx.y * 128;
    const int wm   = (wave >> 1) * 64;
    const int wn   = (wave & 1) * 64;
    const int kchunk = K / S;
    const int kbeg = blockIdx.z * kchunk;

    f32x4_t acc[4][4] = {};

    for (int k0 = kbeg; k0 < kbeg + kchunk; k0 += 32) {
#pragma unroll
        for (int p = 0; p < 2; ++p) {
            const int lin = p * 64 + lane;
            int row = wave * 32 + (lin >> 2);
            int gr  = m0 + row; if (gr > M - 1) gr = M - 1;
            gl_lds16(Abf + (size_t)gr * K + k0 + (lin & 3) * 8, Als + wave * 1024 + p * 512);
        }
#pragma unroll
        for (int p = 0; p < 2; ++p) {
            const int lin = p * 64 + lane;
            const int row = wave * 32 + (lin >> 2);
            gl_lds16(Wt + (size_t)(n0 + row) * K + k0 + (lin & 3) * 8,
                     Bls + wave * 1024 + p * 512);
        }
        __syncthreads();

        bf16x8_t af[4], bfr[4];
#pragma unroll
        for (int i = 0; i < 4; ++i)
            af[i] = *(const bf16x8_t*)(Als + (wm + i * 16 + c16) * 32 + quad * 8);
#pragma unroll
        for (int j = 0; j < 4; ++j)
            bfr[j] = *(const bf16x8_t*)(Bls + (wn + j * 16 + c16) * 32 + quad * 8);
#pragma unroll
        for (int i = 0; i < 4; ++i)
#pragma unroll
            for (int j = 0; j < 4; ++j)
                acc[i][j] = __builtin_amdgcn_mfma_f32_16x16x32_bf16(af[i], bfr[j], acc[i][j], 0, 0, 0);
        __syncthreads();
    }

#pragma unroll
    for (int j = 0; j < 4; ++j) {
        const int col = n0 + wn + j * 16 + c16;
#pragma unroll
        for (int i = 0; i < 4; ++i) {
            const int rowb = m0 + wm + i * 16 + quad * 4;
#pragma unroll
            for (int r = 0; r < 4; ++r) {
                const int row = rowb + r;
                if (row < M) atomicAdd(&Cc[(size_t)row * N + col], acc[i][j][r]);
            }
        }
    }
}

// ---------------------------------------------------------------------------
// MFMA flash attention, direct-global operand feed (no K/V/Q LDS staging,
// no barriers in the K-loop). K-split S=2; grid (10, 12, B*2): b=z&3, s=z>>2.
// V pre-transposed in global (vtb). LDS: Ps (wave-private) + bias tables.
// Writes unnormalized partial O (bf16) + per-(b,h,q) m,l.
// ---------------------------------------------------------------------------
__global__ __launch_bounds__(256)
void attn_part_kernel(const __hip_bfloat16* __restrict__ Qb,
                      const __hip_bfloat16* __restrict__ Kb,
                      const __hip_bfloat16* __restrict__ Vtb,
                      const int* __restrict__ cx, const int* __restrict__ cy,
                      const void* __restrict__ bias_x,
                      const void* __restrict__ bias_y,
                      __hip_bfloat16* __restrict__ p0,
                      __hip_bfloat16* __restrict__ p1,
                      float* __restrict__ mlbase,
                      const int* __restrict__ flagp)
{
    constexpr int QT = 64, KT = 64;
    constexpr int QROW = 72;
    __shared__ __hip_bfloat16 Ps[QT * QROW];
    __shared__ float bxs[2 * MAXD + 1], bys[2 * MAXD + 1];

    const int f32  = *flagp;
    const int tid  = threadIdx.x;
    const int lane = tid & 63;
    const int wave = tid >> 6;
    const int quad = lane >> 4;
    const int c16  = lane & 15;
    const int h    = blockIdx.y;
    const int b    = blockIdx.z & 3;
    const int s    = blockIdx.z >> 2;
    const int q0   = blockIdx.x * QT;
    const int kbeg = s * 1024;
    const int kend = s ? LK : 1024;

    __hip_bfloat16* Op = s ? p1 : p0;
    float* mp = mlbase + (size_t)s * 2 * ML_CNT;
    float* lp = mp + ML_CNT;

    for (int i = tid; i < 2 * MAXD + 1; i += 256) {
        bxs[i] = ldf(bias_x, (size_t)i * NHEAD + h, f32);
        bys[i] = ldf(bias_y, (size_t)i * NHEAD + h, f32);
    }

    // Loop-invariant Q fragments + q coords (direct global)
    const __hip_bfloat16* qrow = Qb + ((size_t)(b * LQ + q0 + wave * 16 + c16)) * DM + h * DK;
    const bf16x8_t aq0 = *(const bf16x8_t*)(qrow + quad * 8);
    const bf16x8_t aq1 = *(const bf16x8_t*)(qrow + 32 + quad * 8);
    int qx[4], qy[4];
#pragma unroll
    for (int r = 0; r < 4; ++r) {
        const int qi = b * LK + LIM + q0 + wave * 16 + quad * 4 + r;
        qx[r] = cx[qi]; qy[r] = cy[qi];
    }
    const __hip_bfloat16* vrow = Vtb + ((size_t)((b * NHEAD + h) * DK)) * LK;

    __syncthreads();   // bias tables visible

    f32x4_t O[4] = {};
    float m_r[4], l_r[4];
#pragma unroll
    for (int r = 0; r < 4; ++r) { m_r[r] = -1e30f; l_r[r] = 0.f; }

    for (int k0 = kbeg; k0 < kend; k0 += KT) {
        // ---- scores: direct-global K fragments ----
        f32x4_t S[4];
#pragma unroll
        for (int jn = 0; jn < 4; ++jn) {
            int krow = k0 + jn * 16 + c16; if (krow > LK - 1) krow = LK - 1;
            const __hip_bfloat16* kr = Kb + ((size_t)(b * LK + krow)) * DM + h * DK;
            bf16x8_t bk0 = *(const bf16x8_t*)(kr + quad * 8);
            bf16x8_t bk1 = *(const bf16x8_t*)(kr + 32 + quad * 8);
            f32x4_t acc = {0.f, 0.f, 0.f, 0.f};
            acc = __builtin_amdgcn_mfma_f32_16x16x32_bf16(aq0, bk0, acc, 0, 0, 0);
            acc = __builtin_amdgcn_mfma_f32_16x16x32_bf16(aq1, bk1, acc, 0, 0, 0);
            S[jn] = acc;
        }
        // ---- bias + tail mask ----
#pragma unroll
        for (int jn = 0; jn < 4; ++jn) {
            const int kg = k0 + jn * 16 + c16;
            const bool ok = kg < LK;
            const int kgc = ok ? kg : LK - 1;
            const int kx = cx[b * LK + kgc], ky = cy[b * LK + kgc];
#pragma unroll
            for (int r = 0; r < 4; ++r) {
                int rx = min(max(qx[r] - kx, -MAXD), MAXD) + MAXD;
                int ry = min(max(qy[r] - ky, -MAXD), MAXD) + MAXD;
                float v = S[jn][r] + bxs[rx] + bys[ry];
                S[jn][r] = ok ? v : -1e30f;
            }
        }
        // ---- online softmax (registers + shfl over 16-lane row group) ----
        float alpha[4];
#pragma unroll
        for (int r = 0; r < 4; ++r) {
            float mx = fmaxf(fmaxf(S[0][r], S[1][r]), fmaxf(S[2][r], S[3][r]));
            mx = fmaxf(mx, __shfl_xor(mx, 1));
            mx = fmaxf(mx, __shfl_xor(mx, 2));
            mx = fmaxf(mx, __shfl_xor(mx, 4));
            mx = fmaxf(mx, __shfl_xor(mx, 8));
            const float mt = fmaxf(m_r[r], mx);
            const float al = __expf(m_r[r] - mt);
            float sum = 0.f;
#pragma unroll
            for (int jn = 0; jn < 4; ++jn) {
                float p = __expf(S[jn][r] - mt);
                S[jn][r] = p;
                sum += p;
            }
            sum += __shfl_xor(sum, 1);
            sum += __shfl_xor(sum, 2);
            sum += __shfl_xor(sum, 4);
            sum += __shfl_xor(sum, 8);
            m_r[r] = mt;
            l_r[r] = l_r[r] * al + sum;
            alpha[r] = al;
        }
        // ---- P -> LDS (wave-private rows; no barrier) + O rescale ----
#pragma unroll
        for (int jn = 0; jn < 4; ++jn)
#pragma unroll
            for (int r = 0; r < 4; ++r)
                Ps[(wave * 16 + quad * 4 + r) * QROW + jn * 16 + c16] = __float2bfloat16(S[jn][r]);
#pragma unroll
        for (int jd = 0; jd < 4; ++jd)
#pragma unroll
            for (int r = 0; r < 4; ++r) O[jd][r] *= alpha[r];
        // ---- PV: A from Ps, B direct from transposed V in global ----
        bf16x8_t ap0 = *(const bf16x8_t*)(Ps + (wave * 16 + c16) * QROW + quad * 8);
        bf16x8_t ap1 = *(const bf16x8_t*)(Ps + (wave * 16 + c16) * QROW + 32 + quad * 8);
        int kc0 = k0 + quad * 8;      if (kc0 > LK - 8) kc0 = LK - 8;
        int kc1 = k0 + 32 + quad * 8; if (kc1 > LK - 8) kc1 = LK - 8;
#pragma unroll
        for (int jd = 0; jd < 4; ++jd) {
            const __hip_bfloat16* vr = vrow + (size_t)(jd * 16 + c16) * LK;
            bf16x8_t bv0 = *(const bf16x8_t*)(vr + kc0);
            bf16x8_t bv1 = *(const bf16x8_t*)(vr + kc1);
            O[jd] = __builtin_amdgcn_mfma_f32_16x16x32_bf16(ap0, bv0, O[jd], 0, 0, 0);
            O[jd] = __builtin_amdgcn_mfma_f32_16x16x32_bf16(ap1, bv1, O[jd], 0, 0, 0);
        }
    }

    // Epilogue: unnormalized partial O + (m,l)
#pragma unroll
    for (int r = 0; r < 4; ++r) {
        const int ql = wave * 16 + quad * 4 + r;
        const size_t grow = (size_t)(b * LQ + q0 + ql);
#pragma unroll
        for (int jd = 0; jd < 4; ++jd)
            Op[grow * DM + h * DK + jd * 16 + c16] = __float2bfloat16(O[jd][r]);
        if (c16 == 0) {
            size_t mli = ((size_t)b * NHEAD + h) * LQ + q0 + ql;
            mp[mli] = m_r[r];
            lp[mli] = l_r[r];
        }
    }
}

// Merge the two K-splits into ctx (in-place over p0) and zero aof.
__global__ __launch_bounds__(256)
void attn_merge_kernel(const __hip_bfloat16* __restrict__ p0,
                       const __hip_bfloat16* __restrict__ p1,
                       const float* __restrict__ mlbase,
                       __hip_bfloat16* __restrict__ ctx,
                       float* __restrict__ aof)
{
    const int row = blockIdx.x;            // (b,q) flat
    const int b = row / LQ, q = row - b * LQ;
    const int tid = threadIdx.x;
#pragma unroll
    for (int i = 0; i < 3; ++i) {
        const int c = tid + i * 256;
        const int h = c >> 6;
        const size_t mli = ((size_t)b * NHEAD + h) * LQ + q;
        const float m0 = mlbase[mli],              l0 = mlbase[ML_CNT + mli];
        const float m1 = mlbase[2 * ML_CNT + mli], l1 = mlbase[3 * ML_CNT + mli];
        const float mm = fmaxf(m0, m1);
        const float w0 = __expf(m0 - mm), w1 = __expf(m1 - mm);
        const float denom = l0 * w0 + l1 * w1;
        const size_t idx = (size_t)row * DM + c;
        const float v = (b2f(p0[idx]) * w0 + b2f(p1[idx]) * w1) / denom;
        ctx[idx] = __float2bfloat16(v);
        aof[idx] = 0.f;
    }
}

// ---------------------------------------------------------------------------
// LayerNorm over 768 with folded bias: x = A + F32acc + bias2.
//  MODE 0: A = flagged Xin -> bf16 ws out; also zeroes zbuf (next accumulator).
//  MODE 1: A = bf16 Xb     -> flagged-dtype d_out.
// ---------------------------------------------------------------------------
template<int MODE>
__global__ __launch_bounds__(256)
void ln_kernel(const void* __restrict__ Xin,
               const __hip_bfloat16* __restrict__ Xb,
               const float* __restrict__ Xf2f,
               const void* __restrict__ bias2,
               const void* __restrict__ g,
               const void* __restrict__ be,
               __hip_bfloat16* __restrict__ outb,
               void* __restrict__ outv,
               float* __restrict__ zbuf,
               const int* __restrict__ flagp)
{
    __shared__ float red1[256], red2[256];
    const int f32 = *flagp;
    const int row = blockIdx.x;
    const int tid = threadIdx.x;

    float x[3];
#pragma unroll
    for (int i = 0; i < 3; ++i) {
        int c = tid + i * 256;
        size_t idx = (size_t)row * DM + c;
        float a  = (MODE == 0) ? ldf(Xin, idx, f32) : b2f(Xb[idx]);
        x[i] = a + Xf2f[idx] + ldf(bias2, c, f32);
    }
    float s1 = x[0] + x[1] + x[2];
    float s2 = x[0] * x[0] + x[1] * x[1] + x[2] * x[2];
    red1[tid] = s1;
    red2[tid] = s2;
    __syncthreads();
    for (int off = 128; off > 0; off >>= 1) {
        if (tid < off) {
            red1[tid] += red1[tid + off];
            red2[tid] += red2[tid + off];
        }
        __syncthreads();
    }
    float mu   = red1[0] * (1.f / DM);
    float var  = red2[0] * (1.f / DM) - mu * mu;
    float rstd = rsqrtf(var + 1e-5f);
#pragma unroll
    for (int i = 0; i < 3; ++i) {
        int c = tid + i * 256;
        size_t idx = (size_t)row * DM + c;
        float v = (x[i] - mu) * rstd * ldf(g, c, f32) + ldf(be, c, f32);
        if (MODE == 0) {
            outb[idx] = __float2bfloat16(v);
            zbuf[idx] = 0.f;
        } else {
            if (f32) ((float*)outv)[idx] = v;
            else     ((__hip_bfloat16*)outv)[idx] = __float2bfloat16(v);
        }
    }
}

// ---------------------------------------------------------------------------
extern "C" void kernel_launch(void* const* d_in, const int* in_sizes, int n_in,
                              void* d_out, int out_size, void* d_ws, size_t ws_size,
                              hipStream_t stream)
{
    const void* docqa = d_in[0];
    const void* im    = d_in[1];
    const int* dqx = (const int*)d_in[2];
    const int* dqy = (const int*)d_in[3];
    const int* imx = (const int*)d_in[4];
    const int* imy = (const int*)d_in[5];
    const void* Wq = d_in[6];
    const void* bq = d_in[7];
    const void* Wk = d_in[8];
    const void* bk = d_in[9];
    const void* Wv = d_in[10];
    const void* bv = d_in[11];
    const void* Wo = d_in[12];
    const void* bo = d_in[13];
    const void* bias_x = d_in[14];
    const void* bias_y = d_in[15];
    const void* W1 = d_in[16];
    const void* b1 = d_in[17];
    const void* W2 = d_in[18];
    const void* b2 = d_in[19];
    const void* g1  = d_in[20];
    const void* be1 = d_in[21];
    const void* g2  = d_in[22];
    const void* be2 = d_in[23];

    // Workspace pool: 39.6 MB, proven since round 3 (DO NOT GROW).
    //   flag @0; qb 3.93M; kb 11.89M; vtb 11.89M; cb 11.89M   [bytes]
    // cb carve (byte offsets), lifetimes stream-sequenced:
    //   [0, 3.54M)      Wt3         (dead after qkv)
    //   [0, 3.93M)      p0 -> ctx -> src1
    //   [3.93, 7.86M)   p1          (dead after merge)
    //   [7.86, 8.36M)   ml          (dead after merge)
    //   [8.36, 9.54M)   WtO         (dead after skWo)
    //   [9.54, 9.61M)   cx,cy       (dead after attn)
    //   [3.93, 11.79M)  fof f32     (zeroed in LN1, after all of the above die)
    // vtb: V^T -> aof f32 -> W1t[0,4.72M)+W2t[4.72,9.44M)
    // qb+kb: q,k -> mid bf16 (15.73M <= 15.82M)
    char* w = (char*)d_ws;
    int*            flagp = (int*)w;
    __hip_bfloat16* qb  = (__hip_bfloat16*)(w + 256);
    __hip_bfloat16* kb  = qb + (size_t)M_DOC  * DM;
    __hip_bfloat16* vtb = kb + (size_t)M_FULL * DM;
    __hip_bfloat16* cb  = vtb + (size_t)M_FULL * DM;
    char* cbB = (char*)cb;

    __hip_bfloat16* Wt3  = cb;
    __hip_bfloat16* p0   = cb;
    __hip_bfloat16* p1   = (__hip_bfloat16*)(cbB + 3932160);
    float*          mlb  = (float*)(cbB + 7864320);
    __hip_bfloat16* WtO  = (__hip_bfloat16*)(cbB + 8355840);
    int*            cxp  = (int*)(cbB + 9535488);
    int*            cyp  = cxp + (size_t)B * LK;
    __hip_bfloat16* ctx  = cb;
    __hip_bfloat16* src1 = cb;
    float*          fof  = (float*)(cbB + 3932160);
    float*          aof  = (float*)vtb;
    __hip_bfloat16* W1t  = vtb;
    __hip_bfloat16* W2t  = vtb + (size_t)DFF * DM;
    __hip_bfloat16* mid  = qb;

    dim3 blk(256);

    // flag + fused coord arrays
    prep_kernel<<<dim3(32), blk, 0, stream>>>(g1, flagp, dqx, dqy, imx, imy, cxp, cyp);
    // attention-side weight transposes
    wtransA_kernel<<<dim3(4 * 576), blk, 0, stream>>>(Wq, Wk, Wv, Wo, Wt3, WtO, flagp);
    // fused q/k/v projection (V written transposed per (b,h))
    qkv_gemm<<<dim3(3 * DM / 128, (M_FULL + 127) / 128), blk, 0, stream>>>(
        im, docqa, Wt3, bq, bk, bv, qb, kb, vtb, flagp);
    // attention, K-split S=2, direct-global operand feed
    attn_part_kernel<<<dim3(LQ / 64, NHEAD, B * 2), blk, 0, stream>>>(
        qb, kb, vtb, cxp, cyp, bias_x, bias_y, p0, p1, mlb, flagp);
    // merge partials -> ctx; zero aof (v dead)
    attn_merge_kernel<<<dim3(M_DOC), blk, 0, stream>>>(p0, p1, mlb, ctx, aof);
    // attn_out: split-K S=4 atomics into aof. bo folded into LN1.
    sk_gemm<<<dim3(DM / 128, M_DOC / 128, 4), blk, 0, stream>>>(
        ctx, WtO, aof, M_DOC, DM, DM, 4);
    // src1 = LN(docqa + aof + bo); also zero fof
    ln_kernel<0><<<dim3(M_DOC), blk, 0, stream>>>(
        docqa, nullptr, aof, bo, g1, be1, src1, nullptr, fof, flagp);
    // FFN weight transposes (overwrite dead aof region)
    wtransW_kernel<<<dim3(2 * 2304), blk, 0, stream>>>(W1, W2, W1t, W2t, flagp);
    // mid = relu(src1 @ W1 + b1)
    mfma_gemm_relu<<<dim3(DFF / 128, M_DOC / 128), blk, 0, stream>>>(
        src1, W1t, b1, mid, flagp, M_DOC, DFF, DM);
    // ffn: split-K S=4 atomics into fof. b2 folded into LN2.
    sk_gemm<<<dim3(DM / 128, M_DOC / 128, 4), blk, 0, stream>>>(
        mid, W2t, fof, M_DOC, DM, DFF, 4);
    // out = LN(src1 + fof + b2)
    ln_kernel<1><<<dim3(M_DOC), blk, 0, stream>>>(
        nullptr, src1, fof, b2, g2, be2, nullptr, d_out, nullptr, flagp);
}